// Round 11
// baseline (193.590 us; speedup 1.0000x reference)
//
#include <hip/hip_runtime.h>

#define SEQ 4096
#define DM 1024
#define NH 16
#define DK 64

typedef _Float16 half8 __attribute__((ext_vector_type(8)));
typedef _Float16 half4v __attribute__((ext_vector_type(4)));
typedef float f32x4 __attribute__((ext_vector_type(4)));

#define MFMA16(a, b, c) __builtin_amdgcn_mfma_f32_16x16x32_f16((a), (b), (c), 0, 0, 0)
#define GLOAD_LDS(g, l)                                                                  \
    __builtin_amdgcn_global_load_lds((const __attribute__((address_space(1))) void*)(g), \
                                     (__attribute__((address_space(3))) void*)(l), 16, 0, 0)

// all-16-lane max via DPP (VALU pipe, ~5cyc/step) -- replaces 4-deep ds_bpermute chain
__device__ __forceinline__ float dpp_max16(float x) {
    x = fmaxf(x, __int_as_float(__builtin_amdgcn_update_dpp(
                     0, __float_as_int(x), 0xB1, 0xF, 0xF, true)));  // quad_perm xor1
    x = fmaxf(x, __int_as_float(__builtin_amdgcn_update_dpp(
                     0, __float_as_int(x), 0x4E, 0xF, 0xF, true)));  // quad_perm xor2
    x = fmaxf(x, __int_as_float(__builtin_amdgcn_update_dpp(
                     0, __float_as_int(x), 0x124, 0xF, 0xF, true)));  // row_ror:4
    x = fmaxf(x, __int_as_float(__builtin_amdgcn_update_dpp(
                     0, __float_as_int(x), 0x128, 0xF, 0xF, true)));  // row_ror:8
    return x;
}

// ---------------- fp32 -> fp16 conversion (7 tensors in one launch, 16B stores) --------
// R9: fusing this into the GEMMs doubled their staged bytes (their binding constraint).
// Standalone cvt at ~19us (80% HBM eff) is the cheaper way. Keep.
__global__ void cvt_all(const float* __restrict__ q, const float* __restrict__ k,
                        const float* __restrict__ v, const float* __restrict__ wq,
                        const float* __restrict__ wk, const float* __restrict__ wv,
                        const float* __restrict__ wo, _Float16* __restrict__ qh,
                        _Float16* __restrict__ kh, _Float16* __restrict__ vh,
                        _Float16* __restrict__ wqh, _Float16* __restrict__ wkh,
                        _Float16* __restrict__ wvh, _Float16* __restrict__ woh) {
    int z = blockIdx.y;
    const float* src;
    _Float16* dst;
    int n;
    switch (z) {
    case 0: src = q;  dst = qh;  n = SEQ * DM; break;
    case 1: src = k;  dst = kh;  n = SEQ * DM; break;
    case 2: src = v;  dst = vh;  n = SEQ * DM; break;
    case 3: src = wq; dst = wqh; n = DM * DM;  break;
    case 4: src = wk; dst = wkh; n = DM * DM;  break;
    case 5: src = wv; dst = wvh; n = DM * DM;  break;
    default: src = wo; dst = woh; n = DM * DM; break;
    }
    int idx = (blockIdx.x * 256 + threadIdx.x) * 8;
    if (idx >= n) return;
    float4 f0 = *(const float4*)(src + idx);
    float4 f1 = *(const float4*)(src + idx + 4);
    half8 h;
    h[0] = (_Float16)f0.x; h[1] = (_Float16)f0.y; h[2] = (_Float16)f0.z; h[3] = (_Float16)f0.w;
    h[4] = (_Float16)f1.x; h[5] = (_Float16)f1.y; h[6] = (_Float16)f1.z; h[7] = (_Float16)f1.w;
    *(half8*)(dst + idx) = h;
}

// ---------------- m97-structure f16 GEMM, BK=64 (best measured; at structure floor) ----
// R5/R6/R7/R9: dbuf+syncthreads, counted-vmcnt, 256^2 tiles, fused-fp32 staging all
// regress or tie. Effective delivery of this structure is ~22 B/cyc/CU (matches m97's
// own 1470cyc per 96KB/CU step); our 1.5MB/CU -> ~29us + prologue = 40us. Only the
// full 8-phase template escapes this floor; porting it blind is a race trap. Do not touch.
template <int MT>  // M-tile: 128 (qkv) or 64 (out); N-tile fixed 128
__device__ __forceinline__ void gemm_bk64(const _Float16* __restrict__ A,
                                          const _Float16* __restrict__ B, int m0, int n0,
                                          _Float16* As, _Float16* Bs, f32x4 (*acc)[4]) {
    constexpr int MI = MT / 32;
    constexpr int ACH = MT / 64;
    const int tid = threadIdx.x;
    const int wave = tid >> 6, lane = tid & 63;
    const int quad = lane >> 4, l16 = lane & 15;
    const int wr = (wave >> 1) * (MT / 2);
    const int wc = (wave & 1) * 64;
    const int srow = tid >> 2, scol = (tid & 3) * 8;

    for (int k0 = 0; k0 < DM; k0 += 64) {
#pragma unroll
        for (int p = 0; p < 2; ++p) {
            int kc = k0 + p * 32 + scol;
#pragma unroll
            for (int j = 0; j < ACH; ++j)
                GLOAD_LDS(A + (size_t)(m0 + j * 64 + srow) * DM + kc,
                          As + p * (MT * 32) + j * 2048 + tid * 8);
#pragma unroll
            for (int j = 0; j < 2; ++j)
                GLOAD_LDS(B + (size_t)(n0 + j * 64 + srow) * DM + kc,
                          Bs + p * 4096 + j * 2048 + tid * 8);
        }
        __syncthreads();
#pragma unroll
        for (int p = 0; p < 2; ++p) {
            half8 af[MI], bf[4];
#pragma unroll
            for (int mi = 0; mi < MI; ++mi)
                af[mi] = *(const half8*)&As[p * (MT * 32) + (wr + mi * 16 + l16) * 32 + quad * 8];
#pragma unroll
            for (int ni = 0; ni < 4; ++ni)
                bf[ni] = *(const half8*)&Bs[p * 4096 + (wc + ni * 16 + l16) * 32 + quad * 8];
#pragma unroll
            for (int mi = 0; mi < MI; ++mi)
#pragma unroll
                for (int ni = 0; ni < 4; ++ni)
                    acc[mi][ni] = MFMA16(af[mi], bf[ni], acc[mi][ni]);
        }
        __syncthreads();
    }
}

// ---------------- QKV projections: 128x128 tiles, grid (32,8,3) = 3 blocks/CU ----------
__global__ void __launch_bounds__(256, 3) gemm_qkv(
    const _Float16* __restrict__ qh, const _Float16* __restrict__ kh,
    const _Float16* __restrict__ vh, const _Float16* __restrict__ wqh,
    const _Float16* __restrict__ wkh, const _Float16* __restrict__ wvh,
    const float* __restrict__ bq, const float* __restrict__ bk, const float* __restrict__ bv,
    _Float16* __restrict__ Qo, _Float16* __restrict__ Ko, _Float16* __restrict__ Vt) {
    __shared__ _Float16 As[2 * 128 * 32];
    __shared__ _Float16 Bs[2 * 128 * 32];
    int z = blockIdx.z;
    const _Float16 *A, *B;
    const float* bias;
    float scale;
    if (z == 0) { A = qh; B = wqh; bias = bq; scale = 0.125f; }  // 1/sqrt(64)
    else if (z == 1) { A = kh; B = wkh; bias = bk; scale = 1.0f; }
    else { A = vh; B = wvh; bias = bv; scale = 1.0f; }

    int m0 = blockIdx.x * 128;
    int n0 = blockIdx.y * 128;
    f32x4 acc[4][4] = {};
    gemm_bk64<128>(A, B, m0, n0, As, Bs, acc);

    const int tid = threadIdx.x;
    const int wave = tid >> 6, lane = tid & 63;
    const int quad = lane >> 4, l16 = lane & 15;
    const int wr = (wave >> 1) * 64;
    const int wc = (wave & 1) * 64;
    float bs[4];
#pragma unroll
    for (int ni = 0; ni < 4; ++ni) bs[ni] = bias[n0 + wc + ni * 16 + l16];

    if (z < 2) {
        _Float16* C = (z == 0) ? Qo : Ko;
#pragma unroll
        for (int mi = 0; mi < 4; ++mi)
#pragma unroll
            for (int ni = 0; ni < 4; ++ni) {
                int m = m0 + wr + mi * 16 + quad * 4;
                int n = n0 + wc + ni * 16 + l16;
#pragma unroll
                for (int r = 0; r < 4; ++r)
                    C[(size_t)(m + r) * DM + n] = (_Float16)((acc[mi][ni][r] + bs[ni]) * scale);
            }
    } else {
#pragma unroll
        for (int mi = 0; mi < 4; ++mi)
#pragma unroll
            for (int ni = 0; ni < 4; ++ni) {
                int m = m0 + wr + mi * 16 + quad * 4;
                int n = n0 + wc + ni * 16 + l16;
                half4v p;
#pragma unroll
                for (int r = 0; r < 4; ++r) p[r] = (_Float16)(acc[mi][ni][r] + bs[ni]);
                *(half4v*)(Vt + (size_t)n * SEQ + m) = p;  // m % 4 == 0 -> 8B aligned
            }
    }
}

// ---------------- output projection: 64x128 tiles, grid (64,8) ------------------------
__global__ void __launch_bounds__(256, 3) gemm_out(const _Float16* __restrict__ Xh,
                                                   const _Float16* __restrict__ woh,
                                                   const float* __restrict__ bo,
                                                   float* __restrict__ out) {
    __shared__ _Float16 As[2 * 64 * 32];
    __shared__ _Float16 Bs[2 * 128 * 32];
    int m0 = blockIdx.x * 64;
    int n0 = blockIdx.y * 128;
    f32x4 acc[2][4] = {};
    gemm_bk64<64>(Xh, woh, m0, n0, As, Bs, acc);

    const int tid = threadIdx.x;
    const int wave = tid >> 6, lane = tid & 63;
    const int quad = lane >> 4, l16 = lane & 15;
    const int wr = (wave >> 1) * 32;
    const int wc = (wave & 1) * 64;
#pragma unroll
    for (int mi = 0; mi < 2; ++mi)
#pragma unroll
        for (int ni = 0; ni < 4; ++ni) {
            int m = m0 + wr + mi * 16 + quad * 4;
            int n = n0 + wc + ni * 16 + l16;
            float b = bo[n];
#pragma unroll
            for (int r = 0; r < 4; ++r) out[(size_t)(m + r) * DM + n] = acc[mi][ni][r] + b;
        }
}

// ---------------- windowed attention: 128 q/block, KVBLK=64, defer-max ----------------
// R10 (win): 128-q blocks, 8 waves, bulk K in LDS, 2 blocks/CU. Loads are no longer
// the pole; per-tile serial overheads are (dpp chain, rescale, bookkeeping). R11:
//   - KVBLK 32->64: ~5 tiles/wave vs ~9. Halves dpp-chain count (3 cheap fmax replace
//     a 4-step dpp chain per 32 keys), rescale events, P-roundtrips, loop overhead.
//     P kept as TWO stride-40 arrays (one per 32-key half) -- R10's proven bank layout.
//   - defer-max (T13, THR=8): skip rescale unless __any(rowmax grew > 8); fires ~once
//     per wave on N(0,1) scores. P <= e^8 fp16-safe; fully-masked-tile poison (p=1)
//     self-heals next real tile via alpha=exp(-1e30-m)=0 wipe (mechanism in use since
//     R0, and defer-max itself passed in R2).
// LDS 48 + 2x10.25 = 68.5KB -> 2 blocks/CU. VGPR est ~110 < 128 cap (512,2).
__global__ void __launch_bounds__(512, 2) attn_kernel(const _Float16* __restrict__ Q,
                                                      const _Float16* __restrict__ K,
                                                      const _Float16* __restrict__ Vt,
                                                      _Float16* __restrict__ X) {
    __shared__ _Float16 Ks[384 * 64];   // 48KB, unit-swizzled (16B unit ^= row&7)
    __shared__ _Float16 P0[8][16][40];  // 10.25KB, keys kt..kt+31
    __shared__ _Float16 P1[8][16][40];  // 10.25KB, keys kt+32..kt+63
    int tid = threadIdx.x;
    int wave = tid >> 6, lane = tid & 63;
    int quad = lane >> 4, l16 = lane & 15;
    int h = blockIdx.y;
    int bx = ((blockIdx.x & 7) << 2) + (blockIdx.x >> 3);  // 32 blocks -> 8 XCD chunks of 4
    int q0b = bx * 128;
    int q0 = q0b + wave * 16;
    int kspan0 = q0b - 128;

    // ---- bulk K staging: 384 rows x 8 units(16B) = 3072 units, 6 per thread ----------
    const _Float16* Kg = K + h * DK;
#pragma unroll
    for (int i = 0; i < 6; ++i) {
        int U = i * 512 + tid;        // linear 16B-unit index in LDS
        int row = U >> 3, u = U & 7;  // rel row, unit-in-row
        int rg = kspan0 + row;
        rg = rg < 0 ? 0 : (rg > SEQ - 1 ? SEQ - 1 : rg);  // clamp: garbage rows are
                                                          // always window-masked
        GLOAD_LDS(Kg + (size_t)rg * DM + ((u ^ (row & 7)) << 3), Ks + U * 8);
    }

    const _Float16* Qp = Q + (size_t)(q0 + l16) * DM + h * DK + quad * 8;
    half8 aq0 = *(const half8*)(Qp);
    half8 aq1 = *(const half8*)(Qp + 32);
    const half8 ones = {(_Float16)1, (_Float16)1, (_Float16)1, (_Float16)1,
                        (_Float16)1, (_Float16)1, (_Float16)1, (_Float16)1};

    float rowM[4], rowL[4];
    f32x4 o[4] = {};
#pragma unroll
    for (int r = 0; r < 4; ++r) { rowM[r] = -__builtin_inff(); rowL[r] = 0.f; }

    // 64-wide tiles; first tile 64-aligned at/below q0-127 (SEQ%64==0 -> keys < SEQ)
    int kstart = (q0 > 127) ? ((q0 - 127) & ~63) : 0;
    int kend = q0 + 143;
    if (kend > SEQ - 1) kend = SEQ - 1;
    const int xk = l16 & 7;

    __syncthreads();  // staging complete (barrier drains vmcnt)

    for (int kt = kstart; kt <= kend; kt += 64) {
        int rel = kt - kspan0;  // in [0, 384), multiple of 64
        // V loads for this tile (8 frags, 2 k-halves) -- consumed at PV much later
        half8 vb0[4], vb1[4];
#pragma unroll
        for (int ni = 0; ni < 4; ++ni) {
            const _Float16* Vp = Vt + (size_t)(h * DK + ni * 16 + l16) * SEQ + kt + quad * 8;
            vb0[ni] = *(const half8*)(Vp);
            vb1[ni] = *(const half8*)(Vp + 32);
        }

        // QK^T over 64 keys (4 cf groups) from LDS K
        f32x4 s[4];
#pragma unroll
        for (int cf = 0; cf < 4; ++cf) {
            int rr = rel + cf * 16 + l16;
            half8 b0 = *(const half8*)&Ks[rr * 64 + ((quad ^ xk) << 3)];
            half8 b1 = *(const half8*)&Ks[rr * 64 + (((quad + 4) ^ xk) << 3)];
            f32x4 z = {};
            z = MFMA16(aq0, b0, z);
            z = MFMA16(aq1, b1, z);
            s[cf] = z;
        }
        // wave-uniform: tile fully inside every row's window?
        // all rows q0..q0+15: kt >= q0+15-127 && kt+63 <= q0+128
        const bool full = (kt >= q0 - 112) && (kt <= q0 + 65);
        float t[4], g = -3e38f;
#pragma unroll
        for (int r = 0; r < 4; ++r) {
            if (!full) {
                int row = q0 + quad * 4 + r;
#pragma unroll
                for (int cf = 0; cf < 4; ++cf) {
                    int key = kt + cf * 16 + l16;
                    if (key < row - 127 || key > row + 128) s[cf][r] = -1e30f;
                }
            }
            float m01 = fmaxf(s[0][r], s[1][r]);
            float m23 = fmaxf(s[2][r], s[3][r]);
            t[r] = dpp_max16(fmaxf(m01, m23));
            g = fmaxf(g, t[r] - rowM[r]);
        }
        // defer-max: rescale only when some row grew by > 8 (first tile: g=inf -> taken)
        if (__any(g > 8.0f)) {
#pragma unroll
            for (int r = 0; r < 4; ++r) {
                float mnew = fmaxf(rowM[r], t[r]);
                float a = __expf(rowM[r] - mnew);
                rowM[r] = mnew;
                rowL[r] *= a;
#pragma unroll
                for (int ni = 0; ni < 4; ++ni) o[ni][r] *= a;
            }
        }
#pragma unroll
        for (int r = 0; r < 4; ++r) {
            int pr = quad * 4 + r;
            P0[wave][pr][l16]      = (_Float16)__expf(s[0][r] - rowM[r]);
            P0[wave][pr][l16 + 16] = (_Float16)__expf(s[1][r] - rowM[r]);
            P1[wave][pr][l16]      = (_Float16)__expf(s[2][r] - rowM[r]);
            P1[wave][pr][l16 + 16] = (_Float16)__expf(s[3][r] - rowM[r]);
        }
        // P: C-layout -> A-operand layout via per-wave LDS round-trip (wave-internal)
        half8 ap0 = *(const half8*)&P0[wave][l16][quad * 8];
        half8 ap1 = *(const half8*)&P1[wave][l16][quad * 8];
        f32x4 ts = {};
        ts = MFMA16(ap0, ones, ts);
        ts = MFMA16(ap1, ones, ts);  // ts[r] = tile row sum over all 64 keys
#pragma unroll
        for (int r = 0; r < 4; ++r) rowL[r] += ts[r];
#pragma unroll
        for (int ni = 0; ni < 4; ++ni) {
            o[ni] = MFMA16(ap0, vb0[ni], o[ni]);
            o[ni] = MFMA16(ap1, vb1[ni], o[ni]);
        }
    }

    float rinv[4];
#pragma unroll
    for (int r = 0; r < 4; ++r) rinv[r] = 1.0f / rowL[r];
#pragma unroll
    for (int ni = 0; ni < 4; ++ni) {
        int n = h * DK + ni * 16 + l16;
#pragma unroll
        for (int r = 0; r < 4; ++r) {
            int m = q0 + quad * 4 + r;
            X[(size_t)m * DM + n] = (_Float16)(o[ni][r] * rinv[r]);
        }
    }
}

extern "C" void kernel_launch(void* const* d_in, const int* in_sizes, int n_in, void* d_out,
                              int out_size, void* d_ws, size_t ws_size, hipStream_t stream) {
    const float* q  = (const float*)d_in[0];
    const float* k  = (const float*)d_in[1];
    const float* v  = (const float*)d_in[2];
    const float* wq = (const float*)d_in[3];
    const float* bq = (const float*)d_in[4];
    const float* wk = (const float*)d_in[5];
    const float* bk = (const float*)d_in[6];
    const float* wv = (const float*)d_in[7];
    const float* bv = (const float*)d_in[8];
    const float* wo = (const float*)d_in[9];
    const float* bo = (const float*)d_in[10];

    const size_t SZ_T = (size_t)SEQ * DM * sizeof(_Float16);  // 8 MB
    const size_t SZ_W = (size_t)DM * DM * sizeof(_Float16);   // 2 MB
    char* p = (char*)d_ws;
    _Float16* qh  = (_Float16*)(p);
    _Float16* kh  = (_Float16*)(p + SZ_T);
    _Float16* vh  = (_Float16*)(p + 2 * SZ_T);
    _Float16* wqh = (_Float16*)(p + 3 * SZ_T);
    _Float16* wkh = (_Float16*)(p + 3 * SZ_T + SZ_W);
    _Float16* wvh = (_Float16*)(p + 3 * SZ_T + 2 * SZ_W);
    _Float16* woh = (_Float16*)(p + 3 * SZ_T + 3 * SZ_W);
    _Float16* Qo  = (_Float16*)(p + 3 * SZ_T + 4 * SZ_W);
    _Float16* Ko  = (_Float16*)(p + 4 * SZ_T + 4 * SZ_W);
    _Float16* Vt  = (_Float16*)(p + 5 * SZ_T + 4 * SZ_W);
    _Float16* Xh  = qh;  // alias: qh dead after gemm_qkv (stream-serialized)

    cvt_all<<<dim3(2048, 7), 256, 0, stream>>>(q, k, v, wq, wk, wv, wo, qh, kh, vh, wqh, wkh,
                                               wvh, woh);
    gemm_qkv<<<dim3(32, 8, 3), 256, 0, stream>>>(qh, kh, vh, wqh, wkh, wvh, bq, bk, bv, Qo, Ko,
                                                 Vt);
    attn_kernel<<<dim3(SEQ / 128, NH), 512, 0, stream>>>(Qo, Ko, Vt, Xh);
    gemm_out<<<dim3(64, 8), 256, 0, stream>>>(Xh, woh, bo, (float*)d_out);
}